// Round 3
// baseline (981.704 us; speedup 1.0000x reference)
//
#include <hip/hip_runtime.h>
#include <stdint.h>

#define AS1 __attribute__((address_space(1)))
#define AS3 __attribute__((address_space(3)))

typedef __bf16 bf16x8 __attribute__((ext_vector_type(8)));
typedef float  f32x4  __attribute__((ext_vector_type(4)));
typedef int    i32x8  __attribute__((ext_vector_type(8)));
typedef float  f32x16 __attribute__((ext_vector_type(16)));

// tanh(x) = 1 - 2/(exp(2x)+1) with fast v_rcp instead of IEEE divide.
// ~6 VALU ops (2 transcendental). |err| ~1e-7, exact at +/-inf.
__device__ __forceinline__ float tanh_fast(float x){
    float e = __expf(2.0f * x);
    return 1.0f - 2.0f * __builtin_amdgcn_rcpf(e + 1.0f);
}

__device__ __forceinline__ unsigned short f2bf(float f){
    unsigned int u = __float_as_uint(f);
    u = (u + 0x7fffu + ((u >> 16) & 1u)) >> 16;   // RNE
    return (unsigned short)u;
}

// unpack 2 bf16 (one uint) -> 2 floats
#define B2F(u, lo, hi) { lo = __uint_as_float((u) << 16); hi = __uint_as_float((u) & 0xffff0000u); }

// ---------------- deterministic compaction of active mask positions ----------------
__global__ void k_pairs(const float* __restrict__ ef, int* __restrict__ pairs){
    int b = blockIdx.x, tid = threadIdx.x;
    __shared__ int s_base, s_woff[4], s_wc[4];
    if (tid == 0) s_base = 0;
    __syncthreads();
    int lane = tid & 63, w = tid >> 6;
    for (int ch = 0; ch < 40; ++ch){
        int pos = ch * 256 + tid;
        bool valid = false;
        if (pos < 10000){
            int r = pos / 100, c = pos - (pos / 100) * 100;
            valid = ef[(size_t)b * 35956 + (size_t)(1 + r) * 356 + 256 + c] != 0.0f;
        }
        unsigned long long bal = __ballot(valid);
        if (lane == 0) s_wc[w] = __popcll(bal);
        __syncthreads();
        if (tid == 0){
            int r = s_base;
            for (int q = 0; q < 4; ++q){ s_woff[q] = r; r += s_wc[q]; }
            s_base = r;
        }
        __syncthreads();
        if (valid){
            int rank = __popcll(bal & ((1ull << lane) - 1ull));
            int o = s_woff[w] + rank;
            if (o < 5000) pairs[b * 5000 + o] = pos;
        }
        __syncthreads();
    }
}

// ---------------- aW1[256:768] -> bf16, transposed [s][col][k] ----------------
__global__ void k_w1t(const float* __restrict__ aW1, unsigned short* __restrict__ w1t){
    int tid = blockIdx.x * 256 + threadIdx.x;          // 65536 threads
    int k8 = tid & 31, c = (tid >> 5) & 1023, s = tid >> 15;
    const float* src = aW1 + (size_t)(256 + s * 256 + k8 * 8) * 1024 + c;
    unsigned int* dst = (unsigned int*)(w1t + (size_t)tid * 8);
#pragma unroll
    for (int jj = 0; jj < 4; ++jj){
        unsigned short lo = f2bf(src[(size_t)(2 * jj) * 1024]);
        unsigned short hi = f2bf(src[(size_t)(2 * jj + 1) * 1024]);
        dst[jj] = (unsigned int)lo | ((unsigned int)hi << 16);
    }
}

// ---------------- aW2 -> fp8 e4m3, blocked into MFMA B-frag plane order ----------------
// element (ct,kt16,h,lane,j) = fp8(aW2[kt16*64 + (lane>>5)*32 + h*16 + j][ct*32 + (lane&31)])
// at w2b[(ct*16+kt16)*2048 + h*1024 + lane*16 + j]
__global__ void k_w2b(const float* __restrict__ aW2, unsigned char* __restrict__ w2b){
    int tid = blockIdx.x * 256 + threadIdx.x;          // 32768 threads
    int lane = tid & 63, kt = (tid >> 6) & 15, ct = tid >> 10;
    int lh = lane >> 5, n = lane & 31;
    int kbase = kt * 64 + lh * 32;
    const float* src = aW2 + (size_t)kbase * 1024 + ct * 32 + n;
    unsigned char* dst = w2b + (size_t)(ct * 16 + kt) * 2048 + lane * 16;
#pragma unroll
    for (int h = 0; h < 2; ++h){
        unsigned int d[4];
#pragma unroll
        for (int jj = 0; jj < 4; ++jj){
            int j = h * 16 + jj * 4;
            int v = __builtin_amdgcn_cvt_pk_fp8_f32(src[(size_t)(j + 0) * 1024],
                                                    src[(size_t)(j + 1) * 1024], 0, false);
            v = __builtin_amdgcn_cvt_pk_fp8_f32(src[(size_t)(j + 2) * 1024],
                                                src[(size_t)(j + 3) * 1024], v, true);
            d[jj] = (unsigned int)v;
        }
        *(uint4*)(dst + h * 1024) = make_uint4(d[0], d[1], d[2], d[3]);
    }
}

// ---------------- g1[b][c] = g_b @ aW1[:256] + ab1 (fp32 exact) ----------------
__global__ void k_g1(const float* __restrict__ ef, const float* __restrict__ aW1,
                     const float* __restrict__ ab1, float* __restrict__ g1o){
    int b = blockIdx.x, t = threadIdx.x;
    __shared__ float gs[256];
    gs[t] = ef[(size_t)b * 35956 + t];
    __syncthreads();
    float a0 = 0.f, a1 = 0.f, a2 = 0.f, a3 = 0.f;
    for (int i = 0; i < 256; ++i){
        float gi = gs[i];
        const float* row = aW1 + (size_t)i * 1024;
        a0 += gi * row[t];       a1 += gi * row[t + 256];
        a2 += gi * row[t + 512]; a3 += gi * row[t + 768];
    }
    float* o = g1o + (size_t)b * 1024;
    o[t] = a0 + ab1[t];             o[t + 256] = a1 + ab1[t + 256];
    o[t + 512] = a2 + ab1[t + 512]; o[t + 768] = a3 + ab1[t + 768];
}

// ---- P{1,2}[b][node][c] = nodes_b @ aW1 slice (+g1 for s=0), stored bf16 ----
__global__ __launch_bounds__(256) void k_p(const float* __restrict__ ef,
        const unsigned short* __restrict__ w1t, unsigned short* __restrict__ P,
        const float* __restrict__ g1){
    __shared__ __align__(16) unsigned short an[112 * 264];
    int blk = blockIdx.x;
    int cb = blk & 15, s = (blk >> 4) & 1, b = blk >> 5;
    int t = threadIdx.x;
    for (int e = t; e < 25600; e += 256){            // stage nodes as bf16
        int row = e >> 8, col = e & 255;
        an[row * 264 + col] = f2bf(ef[(size_t)b * 35956 + (size_t)(1 + row) * 356 + col]);
    }
    for (int e = t; e < 3168; e += 256) an[26400 + e] = 0;  // zero pad rows 100..111
    __syncthreads();
    int w = t >> 6, lane = t & 63, quad = lane >> 4, n = lane & 15;
    int c = cb * 64 + w * 16 + n;
    f32x4 acc[7];
#pragma unroll
    for (int m = 0; m < 7; ++m){ f32x4 z = {0.f, 0.f, 0.f, 0.f}; acc[m] = z; }
    const bf16x8* wp = (const bf16x8*)(w1t + (size_t)(s * 1024 + c) * 256);
#pragma unroll
    for (int kt = 0; kt < 8; ++kt){
        bf16x8 bfr = wp[kt * 4 + quad];
#pragma unroll
        for (int m = 0; m < 7; ++m){
            const bf16x8* ap = (const bf16x8*)(an + (m * 16 + n) * 264 + kt * 32 + quad * 8);
            acc[m] = __builtin_amdgcn_mfma_f32_16x16x32_bf16(*ap, bfr, acc[m], 0, 0, 0);
        }
    }
    float addv = (s == 0) ? g1[(size_t)b * 1024 + c] : 0.0f;
    size_t base = (size_t)s * 3276800 + (size_t)b * 102400;
#pragma unroll
    for (int m = 0; m < 7; ++m){
        int r0 = m * 16 + quad * 4;
#pragma unroll
        for (int r = 0; r < 4; ++r){
            int row = r0 + r;
            if (row < 100) P[base + (size_t)row * 1024 + c] = f2bf(acc[m][r] + addv);
        }
    }
}

// ---------------- value head (tiny, fp32) ----------------
__global__ void k_v(const float* __restrict__ ef,
                    const float* __restrict__ cW1, const float* __restrict__ cb1,
                    const float* __restrict__ cW2, const float* __restrict__ cb2,
                    const float* __restrict__ cW3, const float* __restrict__ cb3,
                    float* __restrict__ out){
    int b = blockIdx.x, t = threadIdx.x;
    __shared__ float gs[256], h1[512], h2[512], wred[4];
    gs[t] = ef[(size_t)b * 35956 + t];
    __syncthreads();
    for (int o = t; o < 512; o += 256){
        float a = cb1[o];
        for (int i = 0; i < 256; ++i) a += gs[i] * cW1[(size_t)i * 512 + o];
        h1[o] = tanh_fast(a);
    }
    __syncthreads();
    for (int o = t; o < 512; o += 256){
        float a = cb2[o];
        for (int i = 0; i < 512; ++i) a += h1[i] * cW2[(size_t)i * 512 + o];
        h2[o] = tanh_fast(a);
    }
    __syncthreads();
    float p = h2[t] * cW3[t] + h2[t + 256] * cW3[t + 256];
    for (int m = 32; m >= 1; m >>= 1) p += __shfl_xor(p, m);
    if ((t & 63) == 0) wred[t >> 6] = p;
    __syncthreads();
    if (t == 0) out[320000 + b] = wred[0] + wred[1] + wred[2] + wred[3] + cb3[0];
}

// ---------------- fused layer1-gather + fp8-MX layer2 GEMM + layer3 dot ----------------
// 4 waves x 32 rows; A (h, fp8) in registers; B via LDS dbuf 2x16KB (64 stages
// of 32 cols x 512 k), 3 blocks/CU.
__global__ __launch_bounds__(256, 3) void k_main(
    const int* __restrict__ pairs,
    const unsigned short* __restrict__ P1, const unsigned short* __restrict__ P2,
    const unsigned char* __restrict__ w2b, const float* __restrict__ ab2,
    const float* __restrict__ aW3, float* __restrict__ logits)
{
    __shared__ __align__(16) unsigned char wbuf[2][16384];
    int b = blockIdx.x / 40, tile = blockIdx.x % 40;
    int t = threadIdx.x, w = t >> 6, lane = t & 63;
    int lrow = lane & 31, lh = lane >> 5;

    // prefetch stage 0 while phase 1 runs (16KB: wave w stages 4KB, lane*16 each)
    {
        const unsigned char* s = w2b + w * 4096 + lane * 16;
        unsigned char* d = &wbuf[0][0] + w * 4096 + lane * 16;
#pragma unroll
        for (int i = 0; i < 4; ++i)
            __builtin_amdgcn_global_load_lds((AS1 void*)(s + i * 1024),
                                             (AS3 void*)(d + i * 1024), 16, 0, 0);
    }

    int grow = tile * 128 + w * 32 + lrow;
    int pidx = pairs[b * 5000 + (grow < 5000 ? grow : 4999)];
    int i1 = pidx / 100, i2 = pidx - i1 * 100;
    const uint4* pa = (const uint4*)(P1 + (((size_t)(b * 100 + i1)) << 10)) + lh * 4;
    const uint4* pb = (const uint4*)(P2 + (((size_t)(b * 100 + i2)) << 10)) + lh * 4;

    // phase 1: h[m=lrow][k] = tanh(P1[i1][k] + P2[i2][k]), packed fp8.
    // af[kt] byte p (p=0..31) = k = kt*64 + lh*32 + p
    i32x8 af[16];
#pragma unroll
    for (int kt = 0; kt < 16; ++kt){
        uint4 qa[4], qb[4];
#pragma unroll
        for (int j = 0; j < 4; ++j){ qa[j] = pa[kt * 8 + j]; qb[j] = pb[kt * 8 + j]; }
        int u[8];
#pragma unroll
        for (int j = 0; j < 4; ++j){
            float a0, a1, b0, b1;
            B2F(qa[j].x, a0, a1); B2F(qb[j].x, b0, b1);
            float t0 = tanh_fast(a0 + b0), t1 = tanh_fast(a1 + b1);
            B2F(qa[j].y, a0, a1); B2F(qb[j].y, b0, b1);
            float t2 = tanh_fast(a0 + b0), t3 = tanh_fast(a1 + b1);
            int v0 = __builtin_amdgcn_cvt_pk_fp8_f32(t0, t1, 0, false);
            v0 = __builtin_amdgcn_cvt_pk_fp8_f32(t2, t3, v0, true);
            B2F(qa[j].z, a0, a1); B2F(qb[j].z, b0, b1);
            t0 = tanh_fast(a0 + b0); t1 = tanh_fast(a1 + b1);
            B2F(qa[j].w, a0, a1); B2F(qb[j].w, b0, b1);
            t2 = tanh_fast(a0 + b0); t3 = tanh_fast(a1 + b1);
            int v1 = __builtin_amdgcn_cvt_pk_fp8_f32(t0, t1, 0, false);
            v1 = __builtin_amdgcn_cvt_pk_fp8_f32(t2, t3, v1, true);
            u[j * 2] = v0; u[j * 2 + 1] = v1;
        }
        i32x8 f = {u[0], u[1], u[2], u[3], u[4], u[5], u[6], u[7]};
        af[kt] = f;
    }

    float prt[16];
#pragma unroll
    for (int r = 0; r < 16; ++r) prt[r] = 0.f;
    f32x16 acc0, acc1;

    // 64 stages: stage s = (ct = s>>1, kh = s&1); buffer parity = s&1
    for (int s = 0; s < 64; ++s){
        int cur = s & 1;
        __syncthreads();                              // wbuf[cur] ready for all waves
        if (s < 63){
            const unsigned char* sp = w2b + (size_t)(s + 1) * 16384 + w * 4096 + lane * 16;
            unsigned char* d = &wbuf[cur ^ 1][0] + w * 4096 + lane * 16;
#pragma unroll
            for (int i = 0; i < 4; ++i)
                __builtin_amdgcn_global_load_lds((AS1 void*)(sp + i * 1024),
                                                 (AS3 void*)(d + i * 1024), 16, 0, 0);
        }
        if ((s & 1) == 0){
#pragma unroll
            for (int r = 0; r < 16; ++r){ acc0[r] = 0.f; acc1[r] = 0.f; }
        }
        const unsigned char* bb = &wbuf[cur][0] + lane * 16;
        int kb = (s & 1) * 8;
#pragma unroll
        for (int k2 = 0; k2 < 8; k2 += 2){
            uint4 q0 = *(const uint4*)(bb + k2 * 2048);
            uint4 q1 = *(const uint4*)(bb + k2 * 2048 + 1024);
            uint4 q2 = *(const uint4*)(bb + (k2 + 1) * 2048);
            uint4 q3 = *(const uint4*)(bb + (k2 + 1) * 2048 + 1024);
            i32x8 b0 = {(int)q0.x, (int)q0.y, (int)q0.z, (int)q0.w,
                        (int)q1.x, (int)q1.y, (int)q1.z, (int)q1.w};
            i32x8 b1 = {(int)q2.x, (int)q2.y, (int)q2.z, (int)q2.w,
                        (int)q3.x, (int)q3.y, (int)q3.z, (int)q3.w};
            acc0 = __builtin_amdgcn_mfma_scale_f32_32x32x64_f8f6f4(
                       af[kb + k2], b0, acc0, 0, 0, 0, 0x7F7F7F7F, 0, 0x7F7F7F7F);
            acc1 = __builtin_amdgcn_mfma_scale_f32_32x32x64_f8f6f4(
                       af[kb + k2 + 1], b1, acc1, 0, 0, 0, 0x7F7F7F7F, 0, 0x7F7F7F7F);
        }
        if (s & 1){
            int ct = s >> 1;
            int c = ct * 32 + lrow;
            float w3 = aW3[c], bias = ab2[c];
#pragma unroll
            for (int r = 0; r < 16; ++r)
                prt[r] += tanh_fast(acc0[r] + acc1[r] + bias) * w3;
        }
    }

    // reduce each reg's partial over the 32 cols (lanes within each half-wave)
#pragma unroll
    for (int r = 0; r < 16; ++r){
        float v = prt[r];
        v += __shfl_xor(v, 1); v += __shfl_xor(v, 2); v += __shfl_xor(v, 4);
        v += __shfl_xor(v, 8); v += __shfl_xor(v, 16);
        if (lrow == 0){
            int row = (r & 3) + 8 * (r >> 2) + 4 * lh;   // 32x32 C/D mapping
            int g = tile * 128 + w * 32 + row;
            if (g < 5000) logits[b * 5000 + g] = v;
        }
    }
}

// ------- zero filled region + softmax over K per batch + scatter -------
__global__ void k_soft(const float* __restrict__ logits, const int* __restrict__ pairs,
                       float* __restrict__ out){
    int b = blockIdx.x, t = threadIdx.x;
    __shared__ float red[4];
    __shared__ float bmS, bsS;
    float* ob = out + (size_t)b * 10000;
    for (int j = t; j < 10000; j += 256) ob[j] = 0.0f;   // replaces k_zero
    const float* lg = logits + b * 5000;
    float m = -1e30f;
    for (int j = t; j < 5000; j += 256) m = fmaxf(m, lg[j]);
    for (int s = 32; s >= 1; s >>= 1) m = fmaxf(m, __shfl_xor(m, s));
    if ((t & 63) == 0) red[t >> 6] = m;
    __syncthreads();
    if (t == 0) bmS = fmaxf(fmaxf(red[0], red[1]), fmaxf(red[2], red[3]));
    __syncthreads();
    float mm = bmS;
    float s = 0.f;
    for (int j = t; j < 5000; j += 256) s += __expf(lg[j] - mm);
    for (int k = 32; k >= 1; k >>= 1) s += __shfl_xor(s, k);
    if ((t & 63) == 0) red[t >> 6] = s;
    __syncthreads();
    if (t == 0) bsS = 1.0f / (red[0] + red[1] + red[2] + red[3]);
    __syncthreads();
    float inv = bsS;
    for (int j = t; j < 5000; j += 256){
        int pos = pairs[b * 5000 + j];
        ob[pos] = __expf(lg[j] - mm) * inv;
    }
}

extern "C" void kernel_launch(void* const* d_in, const int* in_sizes, int n_in,
                              void* d_out, int out_size, void* d_ws, size_t ws_size,
                              hipStream_t stream) {
    (void)in_sizes; (void)n_in; (void)out_size; (void)ws_size;
    const float* ef  = (const float*)d_in[0];
    const float* aW1 = (const float*)d_in[1];
    const float* ab1 = (const float*)d_in[2];
    const float* aW2 = (const float*)d_in[3];
    const float* ab2 = (const float*)d_in[4];
    const float* aW3 = (const float*)d_in[5];
    // d_in[6] = ab3: constant shift, cancels in softmax
    const float* cW1 = (const float*)d_in[7];
    const float* cb1 = (const float*)d_in[8];
    const float* cW2 = (const float*)d_in[9];
    const float* cb2 = (const float*)d_in[10];
    const float* cW3 = (const float*)d_in[11];
    const float* cb3 = (const float*)d_in[12];
    // d_in[13] = K, known = 5000
    float* out = (float*)d_out;
    char* ws = (char*)d_ws;
    int*   pairs  = (int*)(ws + 0);                         // 640,000 B
    float* logits = (float*)(ws + 640000);                  // 640,000 B
    float* g1     = (float*)(ws + 1280000);                 // 131,072 B
    unsigned short* P1 = (unsigned short*)(ws + 1411072);   // 6,553,600 B (bf16)
    unsigned short* P2 = (unsigned short*)(ws + 7964672);   // 6,553,600 B (bf16)
    unsigned char*  w2b = (unsigned char*)(ws + 14518272);  // 1,048,576 B (fp8 blocked)
    unsigned short* w1t = (unsigned short*)(ws + 15566848); // 1,048,576 B

    k_pairs<<<32,   256, 0, stream>>>(ef, pairs);
    k_w1t  <<<256,  256, 0, stream>>>(aW1, w1t);
    k_w2b  <<<128,  256, 0, stream>>>(aW2, w2b);
    k_g1   <<<32,   256, 0, stream>>>(ef, aW1, ab1, g1);
    k_p    <<<1024, 256, 0, stream>>>(ef, w1t, P1, g1);
    k_main <<<1280, 256, 0, stream>>>(pairs, P1, P2, w2b, ab2, aW3, logits);
    k_v    <<<32,   256, 0, stream>>>(ef, cW1, cb1, cW2, cb2, cW3, cb3, out);
    k_soft <<<32,   256, 0, stream>>>(logits, pairs, out);
}

// Round 4
// 375.083 us; speedup vs baseline: 2.6173x; 2.6173x over previous
//
#include <hip/hip_runtime.h>
#include <stdint.h>

#define AS1 __attribute__((address_space(1)))
#define AS3 __attribute__((address_space(3)))

typedef __bf16 bf16x8 __attribute__((ext_vector_type(8)));
typedef float  f32x4  __attribute__((ext_vector_type(4)));
typedef int    i32x8  __attribute__((ext_vector_type(8)));
typedef float  f32x16 __attribute__((ext_vector_type(16)));

// tanh(x) = 1 - 2/(exp(2x)+1) with fast v_rcp. |err| ~1e-7, exact at +/-inf.
__device__ __forceinline__ float tanh_fast(float x){
    float e = __expf(2.0f * x);
    return 1.0f - 2.0f * __builtin_amdgcn_rcpf(e + 1.0f);
}

__device__ __forceinline__ unsigned short f2bf(float f){
    unsigned int u = __float_as_uint(f);
    u = (u + 0x7fffu + ((u >> 16) & 1u)) >> 16;   // RNE
    return (unsigned short)u;
}

// unpack 2 bf16 (one uint) -> 2 floats
#define B2F(u, lo, hi) { lo = __uint_as_float((u) << 16); hi = __uint_as_float((u) & 0xffff0000u); }

// ================= fused prologue: pairs | w1t | w2b | g1 | value-head =================
__global__ __launch_bounds__(256) void k_prep(
    const float* __restrict__ ef,  const float* __restrict__ aW1, const float* __restrict__ ab1,
    const float* __restrict__ aW2,
    const float* __restrict__ cW1, const float* __restrict__ cb1,
    const float* __restrict__ cW2, const float* __restrict__ cb2,
    const float* __restrict__ cW3, const float* __restrict__ cb3,
    int* __restrict__ pairs, unsigned short* __restrict__ w1t,
    unsigned char* __restrict__ w2b, float* __restrict__ g1o, float* __restrict__ out)
{
    int blk = blockIdx.x;
    int t = threadIdx.x;
    __shared__ int s_base, s_woff[4], s_wc[4];
    __shared__ float gs[256];
    __shared__ float h1[512], h2[512], wred[4];

    if (blk < 32){
        // ---- deterministic compaction of active mask positions ----
        int b = blk;
        if (t == 0) s_base = 0;
        __syncthreads();
        int lane = t & 63, w = t >> 6;
        for (int ch = 0; ch < 40; ++ch){
            int pos = ch * 256 + t;
            bool valid = false;
            if (pos < 10000){
                int r = pos / 100, c = pos - (pos / 100) * 100;
                valid = ef[(size_t)b * 35956 + (size_t)(1 + r) * 356 + 256 + c] != 0.0f;
            }
            unsigned long long bal = __ballot(valid);
            if (lane == 0) s_wc[w] = __popcll(bal);
            __syncthreads();
            if (t == 0){
                int r = s_base;
                for (int q = 0; q < 4; ++q){ s_woff[q] = r; r += s_wc[q]; }
                s_base = r;
            }
            __syncthreads();
            if (valid){
                int rank = __popcll(bal & ((1ull << lane) - 1ull));
                int o = s_woff[w] + rank;
                if (o < 5000) pairs[b * 5000 + o] = pos;
            }
            __syncthreads();
        }
    } else if (blk < 288){
        // ---- aW1[256:768] -> bf16, transposed [s][col][k] ----
        int tid = (blk - 32) * 256 + t;                 // 65536 threads
        int k8 = tid & 31, c = (tid >> 5) & 1023, s = tid >> 15;
        const float* src = aW1 + (size_t)(256 + s * 256 + k8 * 8) * 1024 + c;
        unsigned int* dst = (unsigned int*)(w1t + (size_t)tid * 8);
#pragma unroll
        for (int jj = 0; jj < 4; ++jj){
            unsigned short lo = f2bf(src[(size_t)(2 * jj) * 1024]);
            unsigned short hi = f2bf(src[(size_t)(2 * jj + 1) * 1024]);
            dst[jj] = (unsigned int)lo | ((unsigned int)hi << 16);
        }
    } else if (blk < 416){
        // ---- aW2 -> fp8 e4m3, blocked into MFMA B-frag plane order ----
        int tid = (blk - 288) * 256 + t;                // 32768 threads
        int lane = tid & 63, kt = (tid >> 6) & 15, ct = tid >> 10;
        int lh = lane >> 5, n = lane & 31;
        int kbase = kt * 64 + lh * 32;
        const float* src = aW2 + (size_t)kbase * 1024 + ct * 32 + n;
        unsigned char* dst = w2b + (size_t)(ct * 16 + kt) * 2048 + lane * 16;
#pragma unroll
        for (int h = 0; h < 2; ++h){
            unsigned int d[4];
#pragma unroll
            for (int jj = 0; jj < 4; ++jj){
                int j = h * 16 + jj * 4;
                int v = __builtin_amdgcn_cvt_pk_fp8_f32(src[(size_t)(j + 0) * 1024],
                                                        src[(size_t)(j + 1) * 1024], 0, false);
                v = __builtin_amdgcn_cvt_pk_fp8_f32(src[(size_t)(j + 2) * 1024],
                                                    src[(size_t)(j + 3) * 1024], v, true);
                d[jj] = (unsigned int)v;
            }
            *(uint4*)(dst + h * 1024) = make_uint4(d[0], d[1], d[2], d[3]);
        }
    } else if (blk < 448){
        // ---- g1[b][c] = g_b @ aW1[:256] + ab1 (fp32 exact) ----
        int b = blk - 416;
        gs[t] = ef[(size_t)b * 35956 + t];
        __syncthreads();
        float a0 = 0.f, a1 = 0.f, a2 = 0.f, a3 = 0.f;
        for (int i = 0; i < 256; ++i){
            float gi = gs[i];
            const float* row = aW1 + (size_t)i * 1024;
            a0 += gi * row[t];       a1 += gi * row[t + 256];
            a2 += gi * row[t + 512]; a3 += gi * row[t + 768];
        }
        float* o = g1o + (size_t)b * 1024;
        o[t] = a0 + ab1[t];             o[t + 256] = a1 + ab1[t + 256];
        o[t + 512] = a2 + ab1[t + 512]; o[t + 768] = a3 + ab1[t + 768];
    } else {
        // ---- value head (tiny, fp32) ----
        int b = blk - 448;
        gs[t] = ef[(size_t)b * 35956 + t];
        __syncthreads();
        for (int o = t; o < 512; o += 256){
            float a = cb1[o];
            for (int i = 0; i < 256; ++i) a += gs[i] * cW1[(size_t)i * 512 + o];
            h1[o] = tanh_fast(a);
        }
        __syncthreads();
        for (int o = t; o < 512; o += 256){
            float a = cb2[o];
            for (int i = 0; i < 512; ++i) a += h1[i] * cW2[(size_t)i * 512 + o];
            h2[o] = tanh_fast(a);
        }
        __syncthreads();
        float p = h2[t] * cW3[t] + h2[t + 256] * cW3[t + 256];
        for (int m = 32; m >= 1; m >>= 1) p += __shfl_xor(p, m);
        if ((t & 63) == 0) wred[t >> 6] = p;
        __syncthreads();
        if (t == 0) out[320000 + b] = wred[0] + wred[1] + wred[2] + wred[3] + cb3[0];
    }
}

// ---- P{1,2}[b][node][c] = nodes_b @ aW1 slice (+g1 for s=0), stored bf16 ----
__global__ __launch_bounds__(256) void k_p(const float* __restrict__ ef,
        const unsigned short* __restrict__ w1t, unsigned short* __restrict__ P,
        const float* __restrict__ g1){
    __shared__ __align__(16) unsigned short an[112 * 264];
    int blk = blockIdx.x;
    int cb = blk & 15, s = (blk >> 4) & 1, b = blk >> 5;
    int t = threadIdx.x;
    for (int e = t; e < 25600; e += 256){            // stage nodes as bf16
        int row = e >> 8, col = e & 255;
        an[row * 264 + col] = f2bf(ef[(size_t)b * 35956 + (size_t)(1 + row) * 356 + col]);
    }
    for (int e = t; e < 3168; e += 256) an[26400 + e] = 0;  // zero pad rows 100..111
    __syncthreads();
    int w = t >> 6, lane = t & 63, quad = lane >> 4, n = lane & 15;
    int c = cb * 64 + w * 16 + n;
    f32x4 acc[7];
#pragma unroll
    for (int m = 0; m < 7; ++m){ f32x4 z = {0.f, 0.f, 0.f, 0.f}; acc[m] = z; }
    const bf16x8* wp = (const bf16x8*)(w1t + (size_t)(s * 1024 + c) * 256);
#pragma unroll
    for (int kt = 0; kt < 8; ++kt){
        bf16x8 bfr = wp[kt * 4 + quad];
#pragma unroll
        for (int m = 0; m < 7; ++m){
            const bf16x8* ap = (const bf16x8*)(an + (m * 16 + n) * 264 + kt * 32 + quad * 8);
            acc[m] = __builtin_amdgcn_mfma_f32_16x16x32_bf16(*ap, bfr, acc[m], 0, 0, 0);
        }
    }
    float addv = (s == 0) ? g1[(size_t)b * 1024 + c] : 0.0f;
    size_t base = (size_t)s * 3276800 + (size_t)b * 102400;
#pragma unroll
    for (int m = 0; m < 7; ++m){
        int r0 = m * 16 + quad * 4;
#pragma unroll
        for (int r = 0; r < 4; ++r){
            int row = r0 + r;
            if (row < 100) P[base + (size_t)row * 1024 + c] = f2bf(acc[m][r] + addv);
        }
    }
}

// ---------------- fused layer1-gather + fp8-MX layer2 GEMM + layer3 dot ----------------
// 4 waves x 32 rows; A (h, fp8) in 128 VGPRs, COMPILE-TIME indexed (R3's runtime
// kb+k2 index spilled af[] to scratch: 2.6 GB FETCH). B via LDS dbuf 2x16KB with
// fixed buffer roles (wbuf[0]=even k-half, wbuf[1]=odd).
__global__ __launch_bounds__(256, 2) void k_main(
    const int* __restrict__ pairs,
    const unsigned short* __restrict__ P1, const unsigned short* __restrict__ P2,
    const unsigned char* __restrict__ w2b, const float* __restrict__ ab2,
    const float* __restrict__ aW3, float* __restrict__ logits)
{
    __shared__ __align__(16) unsigned char wbuf[2][16384];
    int b = blockIdx.x / 40, tile = blockIdx.x % 40;
    int t = threadIdx.x, w = t >> 6, lane = t & 63;
    int lrow = lane & 31, lh = lane >> 5;
    int soff = w * 4096 + lane * 16;

    // prefetch stage 0 into wbuf[0] while phase 1 runs
    {
        const unsigned char* s = w2b + soff;
        unsigned char* d = &wbuf[0][0] + soff;
#pragma unroll
        for (int i = 0; i < 4; ++i)
            __builtin_amdgcn_global_load_lds((AS1 void*)(s + i * 1024),
                                             (AS3 void*)(d + i * 1024), 16, 0, 0);
    }

    int grow = tile * 128 + w * 32 + lrow;
    int pidx = pairs[b * 5000 + (grow < 5000 ? grow : 4999)];
    int i1 = pidx / 100, i2 = pidx - i1 * 100;
    const uint4* pa = (const uint4*)(P1 + (((size_t)(b * 100 + i1)) << 10)) + lh * 4;
    const uint4* pb = (const uint4*)(P2 + (((size_t)(b * 100 + i2)) << 10)) + lh * 4;

    // phase 1: h[m=lrow][k] = tanh(P1[i1][k] + P2[i2][k]), packed fp8.
    // af[kt] byte p (p=0..31) = k = kt*64 + lh*32 + p
    i32x8 af[16];
#pragma unroll
    for (int kt = 0; kt < 16; ++kt){
        uint4 qa[4], qb[4];
#pragma unroll
        for (int j = 0; j < 4; ++j){ qa[j] = pa[kt * 8 + j]; qb[j] = pb[kt * 8 + j]; }
        int u[8];
#pragma unroll
        for (int j = 0; j < 4; ++j){
            float a0, a1, b0, b1;
            B2F(qa[j].x, a0, a1); B2F(qb[j].x, b0, b1);
            float t0 = tanh_fast(a0 + b0), t1 = tanh_fast(a1 + b1);
            B2F(qa[j].y, a0, a1); B2F(qb[j].y, b0, b1);
            float t2 = tanh_fast(a0 + b0), t3 = tanh_fast(a1 + b1);
            int v0 = __builtin_amdgcn_cvt_pk_fp8_f32(t0, t1, 0, false);
            v0 = __builtin_amdgcn_cvt_pk_fp8_f32(t2, t3, v0, true);
            B2F(qa[j].z, a0, a1); B2F(qb[j].z, b0, b1);
            t0 = tanh_fast(a0 + b0); t1 = tanh_fast(a1 + b1);
            B2F(qa[j].w, a0, a1); B2F(qb[j].w, b0, b1);
            t2 = tanh_fast(a0 + b0); t3 = tanh_fast(a1 + b1);
            int v1 = __builtin_amdgcn_cvt_pk_fp8_f32(t0, t1, 0, false);
            v1 = __builtin_amdgcn_cvt_pk_fp8_f32(t2, t3, v1, true);
            u[j * 2] = v0; u[j * 2 + 1] = v1;
        }
        i32x8 f = {u[0], u[1], u[2], u[3], u[4], u[5], u[6], u[7]};
        af[kt] = f;
    }

    float prt[16];
#pragma unroll
    for (int r = 0; r < 16; ++r) prt[r] = 0.f;
    f32x16 acc0, acc1;

    // 32 col-tiles x 2 k-halves; stage s = ct*2 + kh at w2b + s*16KB
    for (int ct = 0; ct < 32; ++ct){
        // ---- k-half 0: consume wbuf[0], prefetch stage 2ct+1 -> wbuf[1] ----
        __syncthreads();
        {
            const unsigned char* sp = w2b + (size_t)(2 * ct + 1) * 16384 + soff;
            unsigned char* d = &wbuf[1][0] + soff;
#pragma unroll
            for (int i = 0; i < 4; ++i)
                __builtin_amdgcn_global_load_lds((AS1 void*)(sp + i * 1024),
                                                 (AS3 void*)(d + i * 1024), 16, 0, 0);
        }
#pragma unroll
        for (int r = 0; r < 16; ++r){ acc0[r] = 0.f; acc1[r] = 0.f; }
        {
            const unsigned char* bb = &wbuf[0][0] + lane * 16;
#pragma unroll
            for (int k2 = 0; k2 < 8; k2 += 2){
                uint4 q0 = *(const uint4*)(bb + k2 * 2048);
                uint4 q1 = *(const uint4*)(bb + k2 * 2048 + 1024);
                uint4 q2 = *(const uint4*)(bb + (k2 + 1) * 2048);
                uint4 q3 = *(const uint4*)(bb + (k2 + 1) * 2048 + 1024);
                i32x8 b0 = {(int)q0.x, (int)q0.y, (int)q0.z, (int)q0.w,
                            (int)q1.x, (int)q1.y, (int)q1.z, (int)q1.w};
                i32x8 b1 = {(int)q2.x, (int)q2.y, (int)q2.z, (int)q2.w,
                            (int)q3.x, (int)q3.y, (int)q3.z, (int)q3.w};
                acc0 = __builtin_amdgcn_mfma_scale_f32_32x32x64_f8f6f4(
                           af[k2],     b0, acc0, 0, 0, 0, 0x7F7F7F7F, 0, 0x7F7F7F7F);
                acc1 = __builtin_amdgcn_mfma_scale_f32_32x32x64_f8f6f4(
                           af[k2 + 1], b1, acc1, 0, 0, 0, 0x7F7F7F7F, 0, 0x7F7F7F7F);
            }
        }
        // ---- k-half 1: consume wbuf[1], prefetch stage 2ct+2 -> wbuf[0] ----
        __syncthreads();
        if (ct < 31){
            const unsigned char* sp = w2b + (size_t)(2 * ct + 2) * 16384 + soff;
            unsigned char* d = &wbuf[0][0] + soff;
#pragma unroll
            for (int i = 0; i < 4; ++i)
                __builtin_amdgcn_global_load_lds((AS1 void*)(sp + i * 1024),
                                                 (AS3 void*)(d + i * 1024), 16, 0, 0);
        }
        {
            const unsigned char* bb = &wbuf[1][0] + lane * 16;
#pragma unroll
            for (int k2 = 0; k2 < 8; k2 += 2){
                uint4 q0 = *(const uint4*)(bb + k2 * 2048);
                uint4 q1 = *(const uint4*)(bb + k2 * 2048 + 1024);
                uint4 q2 = *(const uint4*)(bb + (k2 + 1) * 2048);
                uint4 q3 = *(const uint4*)(bb + (k2 + 1) * 2048 + 1024);
                i32x8 b0 = {(int)q0.x, (int)q0.y, (int)q0.z, (int)q0.w,
                            (int)q1.x, (int)q1.y, (int)q1.z, (int)q1.w};
                i32x8 b1 = {(int)q2.x, (int)q2.y, (int)q2.z, (int)q2.w,
                            (int)q3.x, (int)q3.y, (int)q3.z, (int)q3.w};
                acc0 = __builtin_amdgcn_mfma_scale_f32_32x32x64_f8f6f4(
                           af[8 + k2],     b0, acc0, 0, 0, 0, 0x7F7F7F7F, 0, 0x7F7F7F7F);
                acc1 = __builtin_amdgcn_mfma_scale_f32_32x32x64_f8f6f4(
                           af[8 + k2 + 1], b1, acc1, 0, 0, 0, 0x7F7F7F7F, 0, 0x7F7F7F7F);
            }
        }
        int c = ct * 32 + lrow;
        float w3 = aW3[c], bias = ab2[c];
#pragma unroll
        for (int r = 0; r < 16; ++r)
            prt[r] += tanh_fast(acc0[r] + acc1[r] + bias) * w3;
    }

    // reduce each reg's partial over the 32 cols (lanes within each half-wave)
#pragma unroll
    for (int r = 0; r < 16; ++r){
        float v = prt[r];
        v += __shfl_xor(v, 1); v += __shfl_xor(v, 2); v += __shfl_xor(v, 4);
        v += __shfl_xor(v, 8); v += __shfl_xor(v, 16);
        if (lrow == 0){
            int row = (r & 3) + 8 * (r >> 2) + 4 * lh;   // 32x32 C/D mapping
            int g = tile * 128 + w * 32 + row;
            if (g < 5000) logits[b * 5000 + g] = v;
        }
    }
}

// ------- zero filled region + softmax over K per batch + scatter -------
__global__ void k_soft(const float* __restrict__ logits, const int* __restrict__ pairs,
                       float* __restrict__ out){
    int b = blockIdx.x, t = threadIdx.x;
    __shared__ float red[4];
    __shared__ float bmS, bsS;
    float* ob = out + (size_t)b * 10000;
    for (int j = t; j < 10000; j += 256) ob[j] = 0.0f;
    const float* lg = logits + b * 5000;
    float m = -1e30f;
    for (int j = t; j < 5000; j += 256) m = fmaxf(m, lg[j]);
    for (int s = 32; s >= 1; s >>= 1) m = fmaxf(m, __shfl_xor(m, s));
    if ((t & 63) == 0) red[t >> 6] = m;
    __syncthreads();
    if (t == 0) bmS = fmaxf(fmaxf(red[0], red[1]), fmaxf(red[2], red[3]));
    __syncthreads();
    float mm = bmS;
    float s = 0.f;
    for (int j = t; j < 5000; j += 256) s += __expf(lg[j] - mm);
    for (int k = 32; k >= 1; k >>= 1) s += __shfl_xor(s, k);
    if ((t & 63) == 0) red[t >> 6] = s;
    __syncthreads();
    if (t == 0) bsS = 1.0f / (red[0] + red[1] + red[2] + red[3]);
    __syncthreads();
    float inv = bsS;
    for (int j = t; j < 5000; j += 256){
        int pos = pairs[b * 5000 + j];
        ob[pos] = __expf(lg[j] - mm) * inv;
    }
}

extern "C" void kernel_launch(void* const* d_in, const int* in_sizes, int n_in,
                              void* d_out, int out_size, void* d_ws, size_t ws_size,
                              hipStream_t stream) {
    (void)in_sizes; (void)n_in; (void)out_size; (void)ws_size;
    const float* ef  = (const float*)d_in[0];
    const float* aW1 = (const float*)d_in[1];
    const float* ab1 = (const float*)d_in[2];
    const float* aW2 = (const float*)d_in[3];
    const float* ab2 = (const float*)d_in[4];
    const float* aW3 = (const float*)d_in[5];
    // d_in[6] = ab3: constant shift, cancels in softmax
    const float* cW1 = (const float*)d_in[7];
    const float* cb1 = (const float*)d_in[8];
    const float* cW2 = (const float*)d_in[9];
    const float* cb2 = (const float*)d_in[10];
    const float* cW3 = (const float*)d_in[11];
    const float* cb3 = (const float*)d_in[12];
    // d_in[13] = K, known = 5000
    float* out = (float*)d_out;
    char* ws = (char*)d_ws;
    int*   pairs  = (int*)(ws + 0);                         // 640,000 B
    float* logits = (float*)(ws + 640000);                  // 640,000 B
    float* g1     = (float*)(ws + 1280000);                 // 131,072 B
    unsigned short* P1 = (unsigned short*)(ws + 1411072);   // 6,553,600 B (bf16)
    unsigned short* P2 = (unsigned short*)(ws + 7964672);   // 6,553,600 B (bf16)
    unsigned char*  w2b = (unsigned char*)(ws + 14518272);  // 1,048,576 B (fp8 blocked)
    unsigned short* w1t = (unsigned short*)(ws + 15566848); // 1,048,576 B

    k_prep <<<480,  256, 0, stream>>>(ef, aW1, ab1, aW2, cW1, cb1, cW2, cb2, cW3, cb3,
                                      pairs, w1t, w2b, g1, out);
    k_p    <<<1024, 256, 0, stream>>>(ef, w1t, P1, g1);
    k_main <<<1280, 256, 0, stream>>>(pairs, P1, P2, w2b, ab2, aW3, logits);
    k_soft <<<32,   256, 0, stream>>>(logits, pairs, out);
}